// Round 1
// baseline (22929.028 us; speedup 1.0000x reference)
//
#include <hip/hip_runtime.h>
#include <hip/hip_cooperative_groups.h>

#define BDIM 64
#define TDIM 1024
#define IDIM 512
#define HDIM 512
#define G4   2048

typedef unsigned short u16;
typedef __attribute__((ext_vector_type(8))) short short8;
typedef __attribute__((ext_vector_type(4))) float f32x4;

__device__ __forceinline__ u16 f2bf(float f) {
    union { float f; unsigned u; } v; v.f = f;
    unsigned u = v.u;
    return (u16)((u + 0x7fffu + ((u >> 16) & 1u)) >> 16);
}
__device__ __forceinline__ float bf2f(u16 h) {
    union { unsigned u; float f; } v; v.u = ((unsigned)h) << 16;
    return v.f;
}
__device__ __forceinline__ float sigmoidf_(float x) {
    return 1.0f / (1.0f + expf(-x));
}

// ---------------------------------------------------------------------------
// prep: cast W_hh -> bf16, bias = b_ih + b_hh, w_full[t] = 0.4*sum(phi cos)/15,
//       zero h double-buffer.
// ---------------------------------------------------------------------------
__global__ void prep_kernel(const float* __restrict__ Whh,
                            const float* __restrict__ bih,
                            const float* __restrict__ bhh,
                            const float* __restrict__ log_phi,
                            const float* __restrict__ gammas,
                            u16* __restrict__ whh_bf,
                            float* __restrict__ bias,
                            float* __restrict__ wfull,
                            u16* __restrict__ hbuf) {
    int idx = blockIdx.x * 256 + threadIdx.x;
    if (idx < G4 * HDIM) whh_bf[idx] = f2bf(Whh[idx]);
    if (idx < G4) bias[idx] = bih[idx] + bhh[idx];
    if (idx < 2 * BDIM * HDIM) hbuf[idx] = 0;
    if (idx < TDIM) {
        float acc = 0.0f;
        #pragma unroll
        for (int m = 0; m < 15; ++m) {
            float lp = log_phi[m];
            float sp = (lp > 15.0f) ? lp : log1pf(expf(lp));
            acc += sp * cosf((float)idx * gammas[m]);
        }
        wfull[idx] = 0.4f * acc / 15.0f;
    }
}

// ---------------------------------------------------------------------------
// xproj GEMM: [65536 x 2048] = x[65536 x 512] * W_ih[2048 x 512]^T + bias
// bf16 MFMA 16x16x32, 128x128 tile, BK=64, XOR-swizzled LDS.
// Output layout: xproj[t][b][n] bf16  (t-major so the scan reads contiguous).
// ---------------------------------------------------------------------------
__global__ __launch_bounds__(256) void xproj_gemm(
        const float* __restrict__ X, const float* __restrict__ Wih,
        const float* __restrict__ bias, u16* __restrict__ xproj) {
    const int tid  = threadIdx.x;
    const int m0   = blockIdx.x * 128;   // 0..511 tiles
    const int n0   = blockIdx.y * 128;   // 0..15 tiles
    const int lane = tid & 63, w = tid >> 6;
    const int l16  = lane & 15, lhi = lane >> 4;
    const int wr   = w >> 1, wc = w & 1;

    __shared__ u16 As[128 * 64];
    __shared__ u16 Bs[128 * 64];

    f32x4 acc[4][4];
    #pragma unroll
    for (int i = 0; i < 4; ++i)
        #pragma unroll
        for (int j = 0; j < 4; ++j) acc[i][j] = (f32x4){0.f, 0.f, 0.f, 0.f};

    for (int kt = 0; kt < 8; ++kt) {
        const int k0 = kt * 64;
        __syncthreads();
        // stage A (x fp32 -> bf16), 128 rows x 8 octs of 8
        #pragma unroll
        for (int p = 0; p < 4; ++p) {
            int g = p * 256 + tid;
            int row = g >> 3, oct = g & 7;
            const float* src = X + (size_t)(m0 + row) * IDIM + k0 + oct * 8;
            float4 v0 = *(const float4*)src;
            float4 v1 = *(const float4*)(src + 4);
            short8 u;
            u[0] = (short)f2bf(v0.x); u[1] = (short)f2bf(v0.y);
            u[2] = (short)f2bf(v0.z); u[3] = (short)f2bf(v0.w);
            u[4] = (short)f2bf(v1.x); u[5] = (short)f2bf(v1.y);
            u[6] = (short)f2bf(v1.z); u[7] = (short)f2bf(v1.w);
            int so = (oct ^ (row & 7)) * 8;
            *(short8*)&As[row * 64 + so] = u;
        }
        // stage B (W_ih fp32 -> bf16)
        #pragma unroll
        for (int p = 0; p < 4; ++p) {
            int g = p * 256 + tid;
            int row = g >> 3, oct = g & 7;
            const float* src = Wih + (size_t)(n0 + row) * IDIM + k0 + oct * 8;
            float4 v0 = *(const float4*)src;
            float4 v1 = *(const float4*)(src + 4);
            short8 u;
            u[0] = (short)f2bf(v0.x); u[1] = (short)f2bf(v0.y);
            u[2] = (short)f2bf(v0.z); u[3] = (short)f2bf(v0.w);
            u[4] = (short)f2bf(v1.x); u[5] = (short)f2bf(v1.y);
            u[6] = (short)f2bf(v1.z); u[7] = (short)f2bf(v1.w);
            int so = (oct ^ (row & 7)) * 8;
            *(short8*)&Bs[row * 64 + so] = u;
        }
        __syncthreads();
        #pragma unroll
        for (int ks = 0; ks < 2; ++ks) {
            short8 a[4], b[4];
            #pragma unroll
            for (int ai = 0; ai < 4; ++ai) {
                int row = 64 * wr + 16 * ai + l16;
                int oct = (4 * ks + lhi) ^ (row & 7);
                a[ai] = *(const short8*)&As[row * 64 + oct * 8];
            }
            #pragma unroll
            for (int bi = 0; bi < 4; ++bi) {
                int row = 64 * wc + 16 * bi + l16;
                int oct = (4 * ks + lhi) ^ (row & 7);
                b[bi] = *(const short8*)&Bs[row * 64 + oct * 8];
            }
            #pragma unroll
            for (int ai = 0; ai < 4; ++ai)
                #pragma unroll
                for (int bi = 0; bi < 4; ++bi)
                    acc[ai][bi] = __builtin_amdgcn_mfma_f32_16x16x32_bf16(
                        a[ai], b[bi], acc[ai][bi], 0, 0, 0);
        }
    }
    // epilogue: D(row=4*lhi+r, col=l16) -> xproj[t][b][n] bf16, + bias
    float bv[4];
    #pragma unroll
    for (int bi = 0; bi < 4; ++bi) bv[bi] = bias[n0 + 64 * wc + 16 * bi + l16];
    #pragma unroll
    for (int ai = 0; ai < 4; ++ai) {
        int grow_base = m0 + 64 * wr + 16 * ai + 4 * lhi;
        #pragma unroll
        for (int bi = 0; bi < 4; ++bi) {
            int gcol = n0 + 64 * wc + 16 * bi + l16;
            #pragma unroll
            for (int r = 0; r < 4; ++r) {
                int grow = grow_base + r;
                int b = grow >> 10;        // row m = b*1024 + t
                int t = grow & 1023;
                xproj[((size_t)t * BDIM + b) * G4 + gcol] =
                    f2bf(acc[ai][bi][r] + bv[bi]);
            }
        }
    }
}

// ---------------------------------------------------------------------------
// scan: cooperative, 64 blocks x 256 threads.
// block (bg,cg): batches 16*bg..+16, h-cols 32*cg..+32 (gate rows g*512+col).
// W_hh B-fragments live in VGPRs for all 1024 steps; c in registers;
// h exchanged via global double-buffer in MFMA-fragment layout:
//   hbuf[buf][bg(4)][ks(16)][ln(64)][j(8)]  (bf16)
// ---------------------------------------------------------------------------
__global__ __launch_bounds__(256, 1) void scan_kernel(
        const u16* __restrict__ whh_bf, const float* __restrict__ wfull,
        const u16* __restrict__ xproj, u16* __restrict__ hbuf,
        float* __restrict__ out) {
    namespace cg = cooperative_groups;
    cg::grid_group grid = cg::this_grid();

    const int tid = threadIdx.x;
    const int blk = blockIdx.x;      // 0..63
    const int bg  = blk >> 4;        // 0..3   batch group (16 batches)
    const int cgp = blk & 15;        // 0..15  col group (32 h-cols)
    const int b0  = bg * 16;
    const int c0  = cgp * 32;
    const int lane = tid & 63, w = tid >> 6;   // wave w owns gate w
    const int l16 = lane & 15, lhi = lane >> 4;

    __shared__ u16  hfrag[16 * 64 * 8];   // 16 KB: [ks][ln][8]
    __shared__ float gates[16 * 128];     //  8 KB: [batch][gate*32+col]
    __shared__ float wt_s[TDIM];          //  4 KB

    for (int i = tid; i < TDIM; i += 256) wt_s[i] = wfull[i];

    // B-fragment preload (stays in VGPRs): wave w, cols (nt*16+l16)
    short8 Bf0[16], Bf1[16];
    #pragma unroll
    for (int ks = 0; ks < 16; ++ks) {
        int row0 = w * HDIM + c0 + l16;        // gate w, col l16
        int row1 = w * HDIM + c0 + 16 + l16;   // gate w, col 16+l16
        Bf0[ks] = *(const short8*)&whh_bf[(size_t)row0 * HDIM + ks * 32 + lhi * 8];
        Bf1[ks] = *(const short8*)&whh_bf[(size_t)row1 * HDIM + ks * 32 + lhi * 8];
    }

    // elementwise ownership: pairs p=tid and p=tid+256 -> (b = p>>5, j = p&31)
    const int eb0 = tid >> 5;
    const int eb1 = 8 + (tid >> 5);
    const int ej  = tid & 31;
    float c_reg0 = 0.0f, c_reg1 = 0.0f;

    __syncthreads();

    for (int t = 0; t < TDIM; ++t) {
        const int cur = t & 1;
        // 1) load h_prev fragments (coalesced 16B)
        const u16* hsrc = hbuf + (size_t)cur * (BDIM * HDIM) + (size_t)bg * (16 * HDIM);
        #pragma unroll
        for (int p = 0; p < 4; ++p) {
            int g = p * 256 + tid;   // ks*64 + ln
            *(short8*)&hfrag[g * 8] = *(const short8*)&hsrc[(size_t)g * 8];
        }
        __syncthreads();

        // 2) gates tile: [16 batches x 32 rows of gate w], K=512
        f32x4 acc0 = {0.f, 0.f, 0.f, 0.f}, acc1 = {0.f, 0.f, 0.f, 0.f};
        #pragma unroll
        for (int ks = 0; ks < 16; ++ks) {
            short8 a = *(const short8*)&hfrag[(ks * 64 + lane) * 8];
            acc0 = __builtin_amdgcn_mfma_f32_16x16x32_bf16(a, Bf0[ks], acc0, 0, 0, 0);
            acc1 = __builtin_amdgcn_mfma_f32_16x16x32_bf16(a, Bf1[ks], acc1, 0, 0, 0);
        }
        #pragma unroll
        for (int r = 0; r < 4; ++r) {
            gates[(4 * lhi + r) * 128 + w * 32 + l16]      = acc0[r];
            gates[(4 * lhi + r) * 128 + w * 32 + 16 + l16] = acc1[r];
        }
        __syncthreads();

        // 3) elementwise LSTM + zeta for 2 (b,j) pairs
        const float wt = wt_s[t];
        const u16* xrow = xproj + (size_t)t * BDIM * G4;
        #pragma unroll
        for (int pp = 0; pp < 2; ++pp) {
            const int b = pp ? eb1 : eb0;
            const int j = ej;
            float cprev = pp ? c_reg1 : c_reg0;
            const u16* xp = xrow + (size_t)(b0 + b) * G4 + c0 + j;
            float gi = gates[b * 128 + 0 * 32 + j] + bf2f(xp[0 * HDIM]);
            float gf = gates[b * 128 + 1 * 32 + j] + bf2f(xp[1 * HDIM]);
            float gg = gates[b * 128 + 2 * 32 + j] + bf2f(xp[2 * HDIM]);
            float go = gates[b * 128 + 3 * 32 + j] + bf2f(xp[3 * HDIM]);
            // h_prev for zeta: hfrag[ks=cgp][ln=b+16*(j>>3)][j&7]
            float hp = bf2f(hfrag[((cgp & 15) * 64 + b + 16 * (j >> 3)) * 8 + (j & 7)]);
            float si = sigmoidf_(gi);
            float sf = sigmoidf_(gf);
            float so = sigmoidf_(go);
            float tg = tanhf(gg);
            float cn = sf * cprev + si * tg;
            float hn = so * tanhf(cn);
            float ho = hn + wt * hp;
            if (pp) c_reg1 = cn; else c_reg0 = cn;

            out[((size_t)(b0 + b) * TDIM + t) * HDIM + c0 + j] = ho;
            int ln = b + 16 * (j >> 3);
            hbuf[(size_t)(cur ^ 1) * (BDIM * HDIM) +
                 ((size_t)bg * 16 + cgp) * 512 + ln * 8 + (j & 7)] = f2bf(ho);
            if (t == TDIM - 1) {
                size_t base = (size_t)BDIM * TDIM * HDIM;
                out[base + (size_t)(b0 + b) * HDIM + c0 + j] = ho;
                out[base + (size_t)BDIM * HDIM + (size_t)(b0 + b) * HDIM + c0 + j] = cn;
            }
        }

        // 4) release h writes, grid barrier, acquire
        __threadfence();
        grid.sync();
        __threadfence();
    }
}

// ---------------------------------------------------------------------------
extern "C" void kernel_launch(void* const* d_in, const int* in_sizes, int n_in,
                              void* d_out, int out_size, void* d_ws, size_t ws_size,
                              hipStream_t stream) {
    const float* x       = (const float*)d_in[0];
    const float* Wih     = (const float*)d_in[1];
    const float* Whh     = (const float*)d_in[2];
    const float* bih     = (const float*)d_in[3];
    const float* bhh     = (const float*)d_in[4];
    const float* log_phi = (const float*)d_in[5];
    const float* gammas  = (const float*)d_in[6];
    float* out = (float*)d_out;

    char* ws = (char*)d_ws;
    u16*   whh_bf = (u16*)(ws);                               // 2 MB
    float* bias   = (float*)(ws + (2u << 20));                // 8 KB
    float* wfull  = (float*)(ws + (2u << 20) + 8192);         // 4 KB
    u16*   hbuf   = (u16*)(ws + (2u << 20) + 16384);          // 128 KB
    u16*   xproj  = (u16*)(ws + (4u << 20));                  // 256 MB

    prep_kernel<<<dim3(4096), dim3(256), 0, stream>>>(
        Whh, bih, bhh, log_phi, gammas, whh_bf, bias, wfull, hbuf);

    xproj_gemm<<<dim3(512, 16), dim3(256), 0, stream>>>(x, Wih, bias, xproj);

    void* args[] = { (void*)&whh_bf, (void*)&wfull, (void*)&xproj,
                     (void*)&hbuf, (void*)&out };
    hipLaunchCooperativeKernel((void*)scan_kernel, dim3(64), dim3(256),
                               args, 0, stream);
}

// Round 2
// 5418.607 us; speedup vs baseline: 4.2315x; 4.2315x over previous
//
#include <hip/hip_runtime.h>
#include <hip/hip_cooperative_groups.h>

#define BDIM 64
#define TDIM 1024
#define IDIM 512
#define HDIM 512
#define G4   2048

typedef unsigned short u16;
typedef unsigned int u32;
typedef unsigned long long u64;
typedef __attribute__((ext_vector_type(8))) short short8;
typedef __attribute__((ext_vector_type(4))) float f32x4;

__device__ __forceinline__ u16 f2bf(float f) {
    union { float f; unsigned u; } v; v.f = f;
    unsigned u = v.u;
    return (u16)((u + 0x7fffu + ((u >> 16) & 1u)) >> 16);
}
__device__ __forceinline__ float bf2f(u16 h) {
    union { unsigned u; float f; } v; v.u = ((unsigned)h) << 16;
    return v.f;
}
__device__ __forceinline__ float sigmoidf_(float x) {
    return 1.0f / (1.0f + expf(-x));
}

// ---------------------------------------------------------------------------
// prep: cast W_hh -> bf16, bias = b_ih + b_hh, w_full[t], zero h dbuf + barrier
// ---------------------------------------------------------------------------
__global__ void prep_kernel(const float* __restrict__ Whh,
                            const float* __restrict__ bih,
                            const float* __restrict__ bhh,
                            const float* __restrict__ log_phi,
                            const float* __restrict__ gammas,
                            u16* __restrict__ whh_bf,
                            float* __restrict__ bias,
                            float* __restrict__ wfull,
                            u16* __restrict__ hbuf,
                            u32* __restrict__ cnt) {
    int idx = blockIdx.x * 256 + threadIdx.x;
    if (idx < G4 * HDIM) whh_bf[idx] = f2bf(Whh[idx]);
    if (idx < G4) bias[idx] = bih[idx] + bhh[idx];
    if (idx < 2 * BDIM * HDIM) hbuf[idx] = 0;
    if (idx < 4) cnt[idx * 32] = 0;
    if (idx < TDIM) {
        float acc = 0.0f;
        #pragma unroll
        for (int m = 0; m < 15; ++m) {
            float lp = log_phi[m];
            float sp = (lp > 15.0f) ? lp : log1pf(expf(lp));
            acc += sp * cosf((float)idx * gammas[m]);
        }
        wfull[idx] = 0.4f * acc / 15.0f;
    }
}

// ---------------------------------------------------------------------------
// xproj GEMM: [65536 x 2048] = x[65536 x 512] * W_ih[2048 x 512]^T + bias
// Output layout: xproj[t][b][n] bf16.
// ---------------------------------------------------------------------------
__global__ __launch_bounds__(256) void xproj_gemm(
        const float* __restrict__ X, const float* __restrict__ Wih,
        const float* __restrict__ bias, u16* __restrict__ xproj) {
    const int tid  = threadIdx.x;
    const int m0   = blockIdx.x * 128;
    const int n0   = blockIdx.y * 128;
    const int lane = tid & 63, w = tid >> 6;
    const int l16  = lane & 15, lhi = lane >> 4;
    const int wr   = w >> 1, wc = w & 1;

    __shared__ u16 As[128 * 64];
    __shared__ u16 Bs[128 * 64];

    f32x4 acc[4][4];
    #pragma unroll
    for (int i = 0; i < 4; ++i)
        #pragma unroll
        for (int j = 0; j < 4; ++j) acc[i][j] = (f32x4){0.f, 0.f, 0.f, 0.f};

    for (int kt = 0; kt < 8; ++kt) {
        const int k0 = kt * 64;
        __syncthreads();
        #pragma unroll
        for (int p = 0; p < 4; ++p) {
            int g = p * 256 + tid;
            int row = g >> 3, oct = g & 7;
            const float* src = X + (size_t)(m0 + row) * IDIM + k0 + oct * 8;
            float4 v0 = *(const float4*)src;
            float4 v1 = *(const float4*)(src + 4);
            short8 u;
            u[0] = (short)f2bf(v0.x); u[1] = (short)f2bf(v0.y);
            u[2] = (short)f2bf(v0.z); u[3] = (short)f2bf(v0.w);
            u[4] = (short)f2bf(v1.x); u[5] = (short)f2bf(v1.y);
            u[6] = (short)f2bf(v1.z); u[7] = (short)f2bf(v1.w);
            int so = (oct ^ (row & 7)) * 8;
            *(short8*)&As[row * 64 + so] = u;
        }
        #pragma unroll
        for (int p = 0; p < 4; ++p) {
            int g = p * 256 + tid;
            int row = g >> 3, oct = g & 7;
            const float* src = Wih + (size_t)(n0 + row) * IDIM + k0 + oct * 8;
            float4 v0 = *(const float4*)src;
            float4 v1 = *(const float4*)(src + 4);
            short8 u;
            u[0] = (short)f2bf(v0.x); u[1] = (short)f2bf(v0.y);
            u[2] = (short)f2bf(v0.z); u[3] = (short)f2bf(v0.w);
            u[4] = (short)f2bf(v1.x); u[5] = (short)f2bf(v1.y);
            u[6] = (short)f2bf(v1.z); u[7] = (short)f2bf(v1.w);
            int so = (oct ^ (row & 7)) * 8;
            *(short8*)&Bs[row * 64 + so] = u;
        }
        __syncthreads();
        #pragma unroll
        for (int ks = 0; ks < 2; ++ks) {
            short8 a[4], b[4];
            #pragma unroll
            for (int ai = 0; ai < 4; ++ai) {
                int row = 64 * wr + 16 * ai + l16;
                int oct = (4 * ks + lhi) ^ (row & 7);
                a[ai] = *(const short8*)&As[row * 64 + oct * 8];
            }
            #pragma unroll
            for (int bi = 0; bi < 4; ++bi) {
                int row = 64 * wc + 16 * bi + l16;
                int oct = (4 * ks + lhi) ^ (row & 7);
                b[bi] = *(const short8*)&Bs[row * 64 + oct * 8];
            }
            #pragma unroll
            for (int ai = 0; ai < 4; ++ai)
                #pragma unroll
                for (int bi = 0; bi < 4; ++bi)
                    acc[ai][bi] = __builtin_amdgcn_mfma_f32_16x16x32_bf16(
                        a[ai], b[bi], acc[ai][bi], 0, 0, 0);
        }
    }
    float bv[4];
    #pragma unroll
    for (int bi = 0; bi < 4; ++bi) bv[bi] = bias[n0 + 64 * wc + 16 * bi + l16];
    #pragma unroll
    for (int ai = 0; ai < 4; ++ai) {
        int grow_base = m0 + 64 * wr + 16 * ai + 4 * lhi;
        #pragma unroll
        for (int bi = 0; bi < 4; ++bi) {
            int gcol = n0 + 64 * wc + 16 * bi + l16;
            #pragma unroll
            for (int r = 0; r < 4; ++r) {
                int grow = grow_base + r;
                int b = grow >> 10;
                int t = grow & 1023;
                xproj[((size_t)t * BDIM + b) * G4 + gcol] =
                    f2bf(acc[ai][bi][r] + bv[bi]);
            }
        }
    }
}

// ---------------------------------------------------------------------------
// scan v2: 64 blocks x 256 threads, cooperative (residency only).
// Per-batch-group (16-block) custom barrier in L3; h exchange via AGENT-scope
// atomics (write-through sc1, no cache flushes). W_hh B-frags in VGPRs.
// hbuf layout: [buf][bg(4)][ks(16)][ln(64)][j(8)] bf16.
// ---------------------------------------------------------------------------
__global__ __launch_bounds__(256, 1) void scan_kernel(
        const u16* __restrict__ whh_bf, const float* __restrict__ wfull,
        const u16* __restrict__ xproj, u16* __restrict__ hbuf,
        u32* __restrict__ cnt, float* __restrict__ out) {
    const int tid = threadIdx.x;
    const int blk = blockIdx.x;      // 0..63
    const int bg  = blk >> 4;        // 0..3
    const int cgp = blk & 15;        // 0..15
    const int b0  = bg * 16;
    const int c0  = cgp * 32;
    const int lane = tid & 63, w = tid >> 6;
    const int l16 = lane & 15, lhi = lane >> 4;

    __shared__ float gates[16 * 128];   // [batch][gate*32+col]
    __shared__ float wt_s[TDIM];

    for (int i = tid; i < TDIM; i += 256) wt_s[i] = wfull[i];

    // W_hh B-fragments resident in VGPRs: wave w = gate w, cols c0+l16, c0+16+l16
    short8 Bf0[16], Bf1[16];
    #pragma unroll
    for (int ks = 0; ks < 16; ++ks) {
        int row0 = w * HDIM + c0 + l16;
        int row1 = w * HDIM + c0 + 16 + l16;
        Bf0[ks] = *(const short8*)&whh_bf[(size_t)row0 * HDIM + ks * 32 + lhi * 8];
        Bf1[ks] = *(const short8*)&whh_bf[(size_t)row1 * HDIM + ks * 32 + lhi * 8];
    }

    // elementwise ownership: thread -> (b = tid>>4, cols j0=2*(tid&15), j0+1)
    const int eb = tid >> 4;
    const int j0 = 2 * (tid & 15);
    const int ln_e = eb + 16 * (j0 >> 3);
    const size_t eidx = ((size_t)bg * 16 + cgp) * 512 + ln_e * 8 + (j0 & 7); // u16 idx, even
    float creg0 = 0.0f, creg1 = 0.0f;

    u32* const mycnt = cnt + bg * 32;

    // prologue: prefetch xproj[t=0]
    u32 xq0, xq1, xq2, xq3;
    {
        const u16* xb = xproj + (size_t)(b0 + eb) * G4 + c0 + j0;
        xq0 = *(const u32*)(xb + 0 * HDIM);
        xq1 = *(const u32*)(xb + 1 * HDIM);
        xq2 = *(const u32*)(xb + 2 * HDIM);
        xq3 = *(const u32*)(xb + 3 * HDIM);
    }

    __syncthreads();

    for (int t = 0; t < TDIM; ++t) {
        const int cur = t & 1;
        const u16* hsrc = hbuf + (size_t)cur * (BDIM * HDIM) + (size_t)bg * (16 * HDIM);

        // A-fragments: direct global(L3)->reg, coherent loads
        short8 a[16];
        #pragma unroll
        for (int ks = 0; ks < 16; ++ks) {
            const u64* p = (const u64*)(hsrc + ks * 512 + lane * 8);
            u64 lo = __hip_atomic_load(p, __ATOMIC_RELAXED, __HIP_MEMORY_SCOPE_AGENT);
            u64 hi = __hip_atomic_load(p + 1, __ATOMIC_RELAXED, __HIP_MEMORY_SCOPE_AGENT);
            union { u64 q[2]; short8 s; } uu; uu.q[0] = lo; uu.q[1] = hi;
            a[ks] = uu.s;
        }
        // zeta h_prev for this thread's two columns
        u32 hpu = __hip_atomic_load(
            (const u32*)(hbuf + (size_t)cur * (BDIM * HDIM) + eidx),
            __ATOMIC_RELAXED, __HIP_MEMORY_SCOPE_AGENT);

        f32x4 acc0 = {0.f, 0.f, 0.f, 0.f}, acc1 = {0.f, 0.f, 0.f, 0.f};
        #pragma unroll
        for (int ks = 0; ks < 16; ++ks) {
            acc0 = __builtin_amdgcn_mfma_f32_16x16x32_bf16(a[ks], Bf0[ks], acc0, 0, 0, 0);
            acc1 = __builtin_amdgcn_mfma_f32_16x16x32_bf16(a[ks], Bf1[ks], acc1, 0, 0, 0);
        }
        #pragma unroll
        for (int r = 0; r < 4; ++r) {
            gates[(4 * lhi + r) * 128 + w * 32 + l16]      = acc0[r];
            gates[(4 * lhi + r) * 128 + w * 32 + 16 + l16] = acc1[r];
        }
        __syncthreads();

        // elementwise LSTM + zeta
        const float wt = wt_s[t];
        float x0 = bf2f((u16)(xq0 & 0xffff)), x1 = bf2f((u16)(xq0 >> 16));
        float f0 = bf2f((u16)(xq1 & 0xffff)), f1 = bf2f((u16)(xq1 >> 16));
        float g0 = bf2f((u16)(xq2 & 0xffff)), g1 = bf2f((u16)(xq2 >> 16));
        float o0 = bf2f((u16)(xq3 & 0xffff)), o1 = bf2f((u16)(xq3 >> 16));

        float gi0 = gates[eb * 128 + 0 * 32 + j0]     + x0;
        float gi1 = gates[eb * 128 + 0 * 32 + j0 + 1] + x1;
        float gf0 = gates[eb * 128 + 1 * 32 + j0]     + f0;
        float gf1 = gates[eb * 128 + 1 * 32 + j0 + 1] + f1;
        float gg0 = gates[eb * 128 + 2 * 32 + j0]     + g0;
        float gg1 = gates[eb * 128 + 2 * 32 + j0 + 1] + g1;
        float go0 = gates[eb * 128 + 3 * 32 + j0]     + o0;
        float go1 = gates[eb * 128 + 3 * 32 + j0 + 1] + o1;

        float hp0 = bf2f((u16)(hpu & 0xffff)), hp1 = bf2f((u16)(hpu >> 16));

        float cn0 = sigmoidf_(gf0) * creg0 + sigmoidf_(gi0) * tanhf(gg0);
        float cn1 = sigmoidf_(gf1) * creg1 + sigmoidf_(gi1) * tanhf(gg1);
        float ho0 = sigmoidf_(go0) * tanhf(cn0) + wt * hp0;
        float ho1 = sigmoidf_(go1) * tanhf(cn1) + wt * hp1;
        creg0 = cn0; creg1 = cn1;

        *(float2*)(out + ((size_t)(b0 + eb) * TDIM + t) * HDIM + c0 + j0) =
            make_float2(ho0, ho1);
        u32 hw = (u32)f2bf(ho0) | ((u32)f2bf(ho1) << 16);
        __hip_atomic_store(
            (u32*)(hbuf + (size_t)(cur ^ 1) * (BDIM * HDIM) + eidx), hw,
            __ATOMIC_RELAXED, __HIP_MEMORY_SCOPE_AGENT);
        if (t == TDIM - 1) {
            size_t base = (size_t)BDIM * TDIM * HDIM;
            *(float2*)(out + base + (size_t)(b0 + eb) * HDIM + c0 + j0) =
                make_float2(ho0, ho1);
            *(float2*)(out + base + (size_t)BDIM * HDIM +
                       (size_t)(b0 + eb) * HDIM + c0 + j0) =
                make_float2(cn0, cn1);
        }

        // flush h stores to L3 before arrival
        asm volatile("s_waitcnt vmcnt(0)" ::: "memory");

        // prefetch xproj[t+1] (overlaps with barrier poll)
        if (t + 1 < TDIM) {
            const u16* xb = xproj + (size_t)(t + 1) * BDIM * G4 +
                            (size_t)(b0 + eb) * G4 + c0 + j0;
            xq0 = *(const u32*)(xb + 0 * HDIM);
            xq1 = *(const u32*)(xb + 1 * HDIM);
            xq2 = *(const u32*)(xb + 2 * HDIM);
            xq3 = *(const u32*)(xb + 3 * HDIM);
        }

        __syncthreads();   // all waves of block flushed before arrival
        if (tid == 0)
            __hip_atomic_fetch_add(mycnt, 1u, __ATOMIC_RELAXED, __HIP_MEMORY_SCOPE_AGENT);
        const u32 target = 16u * (u32)(t + 1);
        while (__hip_atomic_load(mycnt, __ATOMIC_RELAXED, __HIP_MEMORY_SCOPE_AGENT) < target) {}
    }
}

// ---------------------------------------------------------------------------
extern "C" void kernel_launch(void* const* d_in, const int* in_sizes, int n_in,
                              void* d_out, int out_size, void* d_ws, size_t ws_size,
                              hipStream_t stream) {
    const float* x       = (const float*)d_in[0];
    const float* Wih     = (const float*)d_in[1];
    const float* Whh     = (const float*)d_in[2];
    const float* bih     = (const float*)d_in[3];
    const float* bhh     = (const float*)d_in[4];
    const float* log_phi = (const float*)d_in[5];
    const float* gammas  = (const float*)d_in[6];
    float* out = (float*)d_out;

    char* ws = (char*)d_ws;
    u16*   whh_bf = (u16*)(ws);                               // 2 MB
    float* bias   = (float*)(ws + (2u << 20));                // 8 KB
    float* wfull  = (float*)(ws + (2u << 20) + 8192);         // 4 KB
    u32*   cnt    = (u32*)(ws + (2u << 20) + 12288);          // 512 B (4 x 128B)
    u16*   hbuf   = (u16*)(ws + (2u << 20) + 16384);          // 128 KB
    u16*   xproj  = (u16*)(ws + (4u << 20));                  // 256 MB

    prep_kernel<<<dim3(4096), dim3(256), 0, stream>>>(
        Whh, bih, bhh, log_phi, gammas, whh_bf, bias, wfull, hbuf, cnt);

    xproj_gemm<<<dim3(512, 16), dim3(256), 0, stream>>>(x, Wih, bias, xproj);

    void* args[] = { (void*)&whh_bf, (void*)&wfull, (void*)&xproj,
                     (void*)&hbuf, (void*)&cnt, (void*)&out };
    hipLaunchCooperativeKernel((void*)scan_kernel, dim3(64), dim3(256),
                               args, 0, stream);
}

// Round 3
// 4818.273 us; speedup vs baseline: 4.7588x; 1.1246x over previous
//
#include <hip/hip_runtime.h>
#include <hip/hip_cooperative_groups.h>

#define BDIM 64
#define TDIM 1024
#define IDIM 512
#define HDIM 512
#define G4   2048

typedef unsigned short u16;
typedef unsigned int u32;
typedef unsigned long long u64;
typedef __attribute__((ext_vector_type(8))) short short8;
typedef __attribute__((ext_vector_type(4))) float f32x4;

__device__ __forceinline__ u16 f2bf(float f) {
    union { float f; unsigned u; } v; v.f = f;
    unsigned u = v.u;
    return (u16)((u + 0x7fffu + ((u >> 16) & 1u)) >> 16);
}
__device__ __forceinline__ float bf2f(u16 h) {
    union { unsigned u; float f; } v; v.u = ((unsigned)h) << 16;
    return v.f;
}
__device__ __forceinline__ float sigmoidf_(float x) {
    return 1.0f / (1.0f + expf(-x));
}

// ---------------------------------------------------------------------------
// prep: cast W_hh -> bf16, bias = b_ih + b_hh, w_full[t], zero h dbuf + flags
// ---------------------------------------------------------------------------
__global__ void prep_kernel(const float* __restrict__ Whh,
                            const float* __restrict__ bih,
                            const float* __restrict__ bhh,
                            const float* __restrict__ log_phi,
                            const float* __restrict__ gammas,
                            u16* __restrict__ whh_bf,
                            float* __restrict__ bias,
                            float* __restrict__ wfull,
                            u16* __restrict__ hbuf,
                            u32* __restrict__ flags) {
    int idx = blockIdx.x * 256 + threadIdx.x;
    if (idx < G4 * HDIM) whh_bf[idx] = f2bf(Whh[idx]);
    if (idx < G4) bias[idx] = bih[idx] + bhh[idx];
    if (idx < 2 * BDIM * HDIM) hbuf[idx] = 0;
    if (idx < 128) flags[idx] = 0;
    if (idx < TDIM) {
        float acc = 0.0f;
        #pragma unroll
        for (int m = 0; m < 15; ++m) {
            float lp = log_phi[m];
            float sp = (lp > 15.0f) ? lp : log1pf(expf(lp));
            acc += sp * cosf((float)idx * gammas[m]);
        }
        wfull[idx] = 0.4f * acc / 15.0f;
    }
}

// ---------------------------------------------------------------------------
// xproj GEMM: [65536 x 2048] = x[65536 x 512] * W_ih[2048 x 512]^T + bias
// Output layout: xproj[t][b][n] bf16.
// ---------------------------------------------------------------------------
__global__ __launch_bounds__(256) void xproj_gemm(
        const float* __restrict__ X, const float* __restrict__ Wih,
        const float* __restrict__ bias, u16* __restrict__ xproj) {
    const int tid  = threadIdx.x;
    const int m0   = blockIdx.x * 128;
    const int n0   = blockIdx.y * 128;
    const int lane = tid & 63, w = tid >> 6;
    const int l16  = lane & 15, lhi = lane >> 4;
    const int wr   = w >> 1, wc = w & 1;

    __shared__ u16 As[128 * 64];
    __shared__ u16 Bs[128 * 64];

    f32x4 acc[4][4];
    #pragma unroll
    for (int i = 0; i < 4; ++i)
        #pragma unroll
        for (int j = 0; j < 4; ++j) acc[i][j] = (f32x4){0.f, 0.f, 0.f, 0.f};

    for (int kt = 0; kt < 8; ++kt) {
        const int k0 = kt * 64;
        __syncthreads();
        #pragma unroll
        for (int p = 0; p < 4; ++p) {
            int g = p * 256 + tid;
            int row = g >> 3, oct = g & 7;
            const float* src = X + (size_t)(m0 + row) * IDIM + k0 + oct * 8;
            float4 v0 = *(const float4*)src;
            float4 v1 = *(const float4*)(src + 4);
            short8 u;
            u[0] = (short)f2bf(v0.x); u[1] = (short)f2bf(v0.y);
            u[2] = (short)f2bf(v0.z); u[3] = (short)f2bf(v0.w);
            u[4] = (short)f2bf(v1.x); u[5] = (short)f2bf(v1.y);
            u[6] = (short)f2bf(v1.z); u[7] = (short)f2bf(v1.w);
            int so = (oct ^ (row & 7)) * 8;
            *(short8*)&As[row * 64 + so] = u;
        }
        #pragma unroll
        for (int p = 0; p < 4; ++p) {
            int g = p * 256 + tid;
            int row = g >> 3, oct = g & 7;
            const float* src = Wih + (size_t)(n0 + row) * IDIM + k0 + oct * 8;
            float4 v0 = *(const float4*)src;
            float4 v1 = *(const float4*)(src + 4);
            short8 u;
            u[0] = (short)f2bf(v0.x); u[1] = (short)f2bf(v0.y);
            u[2] = (short)f2bf(v0.z); u[3] = (short)f2bf(v0.w);
            u[4] = (short)f2bf(v1.x); u[5] = (short)f2bf(v1.y);
            u[6] = (short)f2bf(v1.z); u[7] = (short)f2bf(v1.w);
            int so = (oct ^ (row & 7)) * 8;
            *(short8*)&Bs[row * 64 + so] = u;
        }
        __syncthreads();
        #pragma unroll
        for (int ks = 0; ks < 2; ++ks) {
            short8 a[4], b[4];
            #pragma unroll
            for (int ai = 0; ai < 4; ++ai) {
                int row = 64 * wr + 16 * ai + l16;
                int oct = (4 * ks + lhi) ^ (row & 7);
                a[ai] = *(const short8*)&As[row * 64 + oct * 8];
            }
            #pragma unroll
            for (int bi = 0; bi < 4; ++bi) {
                int row = 64 * wc + 16 * bi + l16;
                int oct = (4 * ks + lhi) ^ (row & 7);
                b[bi] = *(const short8*)&Bs[row * 64 + oct * 8];
            }
            #pragma unroll
            for (int ai = 0; ai < 4; ++ai)
                #pragma unroll
                for (int bi = 0; bi < 4; ++bi)
                    acc[ai][bi] = __builtin_amdgcn_mfma_f32_16x16x32_bf16(
                        a[ai], b[bi], acc[ai][bi], 0, 0, 0);
        }
    }
    float bv[4];
    #pragma unroll
    for (int bi = 0; bi < 4; ++bi) bv[bi] = bias[n0 + 64 * wc + 16 * bi + l16];
    #pragma unroll
    for (int ai = 0; ai < 4; ++ai) {
        int grow_base = m0 + 64 * wr + 16 * ai + 4 * lhi;
        #pragma unroll
        for (int bi = 0; bi < 4; ++bi) {
            int gcol = n0 + 64 * wc + 16 * bi + l16;
            #pragma unroll
            for (int r = 0; r < 4; ++r) {
                int grow = grow_base + r;
                int b = grow >> 10;
                int t = grow & 1023;
                xproj[((size_t)t * BDIM + b) * G4 + gcol] =
                    f2bf(acc[ai][bi][r] + bv[bi]);
            }
        }
    }
}

// ---------------------------------------------------------------------------
// scan v3: 64 blocks x 256 threads, cooperative (co-residency).
// Per-batch-group barrier = 16-entry flag array (no RMW), polled by wave 0
// only; other waves parked at __syncthreads. h via relaxed AGENT atomics.
// hbuf layout: [buf][bg(4)][ks(16)][ln(64)][j(8)] bf16.
// ---------------------------------------------------------------------------
__global__ __launch_bounds__(256, 1) void scan_kernel(
        const u16* __restrict__ whh_bf, const float* __restrict__ wfull,
        const u16* __restrict__ xproj, u16* __restrict__ hbuf,
        u32* __restrict__ flags, float* __restrict__ out) {
    const int tid = threadIdx.x;
    const int blk = blockIdx.x;      // 0..63
    const int bg  = blk >> 4;        // 0..3
    const int cgp = blk & 15;        // 0..15
    const int b0  = bg * 16;
    const int c0  = cgp * 32;
    const int lane = tid & 63, w = tid >> 6;
    const int l16 = lane & 15, lhi = lane >> 4;

    __shared__ float gates[16 * 128];   // [batch][gate*32+col]
    __shared__ float wt_s[TDIM];

    for (int i = tid; i < TDIM; i += 256) wt_s[i] = wfull[i];

    // W_hh B-fragments resident in regs: wave w = gate w, cols c0+l16, c0+16+l16
    short8 Bf0[16], Bf1[16];
    #pragma unroll
    for (int ks = 0; ks < 16; ++ks) {
        int row0 = w * HDIM + c0 + l16;
        int row1 = w * HDIM + c0 + 16 + l16;
        Bf0[ks] = *(const short8*)&whh_bf[(size_t)row0 * HDIM + ks * 32 + lhi * 8];
        Bf1[ks] = *(const short8*)&whh_bf[(size_t)row1 * HDIM + ks * 32 + lhi * 8];
    }

    // elementwise ownership: thread -> (b = tid>>4, cols j0=2*(tid&15), j0+1)
    const int eb = tid >> 4;
    const int j0 = 2 * (tid & 15);
    const int ln_e = eb + 16 * (j0 >> 3);
    const size_t eidx = ((size_t)bg * 16 + cgp) * 512 + ln_e * 8 + (j0 & 7); // u16 idx, even
    float creg0 = 0.0f, creg1 = 0.0f;

    u32* const gflags = flags + bg * 32;

    // prologue: prefetch xproj[t=0]
    u32 xq0, xq1, xq2, xq3;
    {
        const u16* xb = xproj + (size_t)(b0 + eb) * G4 + c0 + j0;
        xq0 = *(const u32*)(xb + 0 * HDIM);
        xq1 = *(const u32*)(xb + 1 * HDIM);
        xq2 = *(const u32*)(xb + 2 * HDIM);
        xq3 = *(const u32*)(xb + 3 * HDIM);
    }

    __syncthreads();

    for (int t = 0; t < TDIM; ++t) {
        const int cur = t & 1;
        const u16* hsrc = hbuf + (size_t)cur * (BDIM * HDIM) + (size_t)bg * (16 * HDIM);

        // A-fragments: direct L3->reg, coherent loads
        short8 a[16];
        #pragma unroll
        for (int ks = 0; ks < 16; ++ks) {
            const u64* p = (const u64*)(hsrc + ks * 512 + lane * 8);
            u64 lo = __hip_atomic_load(p, __ATOMIC_RELAXED, __HIP_MEMORY_SCOPE_AGENT);
            u64 hi = __hip_atomic_load(p + 1, __ATOMIC_RELAXED, __HIP_MEMORY_SCOPE_AGENT);
            union { u64 q[2]; short8 s; } uu; uu.q[0] = lo; uu.q[1] = hi;
            a[ks] = uu.s;
        }
        // zeta h_prev for this thread's two columns
        u32 hpu = __hip_atomic_load(
            (const u32*)(hbuf + (size_t)cur * (BDIM * HDIM) + eidx),
            __ATOMIC_RELAXED, __HIP_MEMORY_SCOPE_AGENT);

        f32x4 acc0 = {0.f, 0.f, 0.f, 0.f}, acc1 = {0.f, 0.f, 0.f, 0.f};
        #pragma unroll
        for (int ks = 0; ks < 16; ++ks) {
            acc0 = __builtin_amdgcn_mfma_f32_16x16x32_bf16(a[ks], Bf0[ks], acc0, 0, 0, 0);
            acc1 = __builtin_amdgcn_mfma_f32_16x16x32_bf16(a[ks], Bf1[ks], acc1, 0, 0, 0);
        }
        #pragma unroll
        for (int r = 0; r < 4; ++r) {
            gates[(4 * lhi + r) * 128 + w * 32 + l16]      = acc0[r];
            gates[(4 * lhi + r) * 128 + w * 32 + 16 + l16] = acc1[r];
        }
        __syncthreads();

        // elementwise LSTM + zeta
        const float wt = wt_s[t];
        float x0 = bf2f((u16)(xq0 & 0xffff)), x1 = bf2f((u16)(xq0 >> 16));
        float f0 = bf2f((u16)(xq1 & 0xffff)), f1 = bf2f((u16)(xq1 >> 16));
        float g0 = bf2f((u16)(xq2 & 0xffff)), g1 = bf2f((u16)(xq2 >> 16));
        float o0 = bf2f((u16)(xq3 & 0xffff)), o1 = bf2f((u16)(xq3 >> 16));

        float gi0 = gates[eb * 128 + 0 * 32 + j0]     + x0;
        float gi1 = gates[eb * 128 + 0 * 32 + j0 + 1] + x1;
        float gf0 = gates[eb * 128 + 1 * 32 + j0]     + f0;
        float gf1 = gates[eb * 128 + 1 * 32 + j0 + 1] + f1;
        float gg0 = gates[eb * 128 + 2 * 32 + j0]     + g0;
        float gg1 = gates[eb * 128 + 2 * 32 + j0 + 1] + g1;
        float go0 = gates[eb * 128 + 3 * 32 + j0]     + o0;
        float go1 = gates[eb * 128 + 3 * 32 + j0 + 1] + o1;

        float hp0 = bf2f((u16)(hpu & 0xffff)), hp1 = bf2f((u16)(hpu >> 16));

        float cn0 = sigmoidf_(gf0) * creg0 + sigmoidf_(gi0) * tanhf(gg0);
        float cn1 = sigmoidf_(gf1) * creg1 + sigmoidf_(gi1) * tanhf(gg1);
        float ho0 = sigmoidf_(go0) * tanhf(cn0) + wt * hp0;
        float ho1 = sigmoidf_(go1) * tanhf(cn1) + wt * hp1;
        creg0 = cn0; creg1 = cn1;

        // h store first (it is the only store the barrier must cover)
        u32 hw = (u32)f2bf(ho0) | ((u32)f2bf(ho1) << 16);
        __hip_atomic_store(
            (u32*)(hbuf + (size_t)(cur ^ 1) * (BDIM * HDIM) + eidx), hw,
            __ATOMIC_RELAXED, __HIP_MEMORY_SCOPE_AGENT);
        asm volatile("s_waitcnt vmcnt(0)" ::: "memory");
        __syncthreads();            // all threads' h stores acked at L3

        // arrival: one plain flag store per block (no RMW)
        if (t + 1 < TDIM && tid == 0)
            __hip_atomic_store(&gflags[cgp], (u32)(t + 1),
                               __ATOMIC_RELAXED, __HIP_MEMORY_SCOPE_AGENT);

        // deferred off-critical-path work: out store + xproj prefetch
        *(float2*)(out + ((size_t)(b0 + eb) * TDIM + t) * HDIM + c0 + j0) =
            make_float2(ho0, ho1);
        if (t == TDIM - 1) {
            size_t base = (size_t)BDIM * TDIM * HDIM;
            *(float2*)(out + base + (size_t)(b0 + eb) * HDIM + c0 + j0) =
                make_float2(ho0, ho1);
            *(float2*)(out + base + (size_t)BDIM * HDIM +
                       (size_t)(b0 + eb) * HDIM + c0 + j0) =
                make_float2(cn0, cn1);
            break;
        }
        {
            const u16* xb = xproj + (size_t)(t + 1) * BDIM * G4 +
                            (size_t)(b0 + eb) * G4 + c0 + j0;
            xq0 = *(const u32*)(xb + 0 * HDIM);
            xq1 = *(const u32*)(xb + 1 * HDIM);
            xq2 = *(const u32*)(xb + 2 * HDIM);
            xq3 = *(const u32*)(xb + 3 * HDIM);
        }

        // wave 0 polls the 16 group flags; other waves park at the barrier
        if (w == 0) {
            const u32 target = (u32)(t + 1);
            u32 v;
            do {
                v = (l16 == lane)   // lanes 0..15 load, others forced pass
                    ? __hip_atomic_load(&gflags[lane], __ATOMIC_RELAXED,
                                        __HIP_MEMORY_SCOPE_AGENT)
                    : 0xffffffffu;
            } while (!__all(v >= target));
        }
        __syncthreads();
    }
}

// ---------------------------------------------------------------------------
extern "C" void kernel_launch(void* const* d_in, const int* in_sizes, int n_in,
                              void* d_out, int out_size, void* d_ws, size_t ws_size,
                              hipStream_t stream) {
    const float* x       = (const float*)d_in[0];
    const float* Wih     = (const float*)d_in[1];
    const float* Whh     = (const float*)d_in[2];
    const float* bih     = (const float*)d_in[3];
    const float* bhh     = (const float*)d_in[4];
    const float* log_phi = (const float*)d_in[5];
    const float* gammas  = (const float*)d_in[6];
    float* out = (float*)d_out;

    char* ws = (char*)d_ws;
    u16*   whh_bf = (u16*)(ws);                               // 2 MB
    float* bias   = (float*)(ws + (2u << 20));                // 8 KB
    float* wfull  = (float*)(ws + (2u << 20) + 8192);         // 4 KB
    u32*   flags  = (u32*)(ws + (2u << 20) + 12288);          // 512 B (4 x 128B)
    u16*   hbuf   = (u16*)(ws + (2u << 20) + 16384);          // 128 KB
    u16*   xproj  = (u16*)(ws + (4u << 20));                  // 256 MB

    prep_kernel<<<dim3(4096), dim3(256), 0, stream>>>(
        Whh, bih, bhh, log_phi, gammas, whh_bf, bias, wfull, hbuf, flags);

    xproj_gemm<<<dim3(512, 16), dim3(256), 0, stream>>>(x, Wih, bias, xproj);

    void* args[] = { (void*)&whh_bf, (void*)&wfull, (void*)&xproj,
                     (void*)&hbuf, (void*)&flags, (void*)&out };
    hipLaunchCooperativeKernel((void*)scan_kernel, dim3(64), dim3(256),
                               args, 0, stream);
}